// Round 6
// baseline (248.375 us; speedup 1.0000x reference)
//
#include <hip/hip_runtime.h>
#include <stdint.h>

typedef unsigned short u16;
typedef short bf16x8 __attribute__((ext_vector_type(8)));
typedef short bf16x4 __attribute__((ext_vector_type(4)));
typedef float f32x4 __attribute__((ext_vector_type(4)));

#define MB (1u<<20)
#define CL2 0.18033688f   // log2(e)/sqrt(DK)

static __device__ __forceinline__ u16 f2bf(float x){
  union { float f; unsigned u; } v; v.f = x;
  return (u16)((v.u + 0x7FFFu + ((v.u >> 16) & 1u)) >> 16);
}
static __device__ __forceinline__ float bf2f(u16 x){
  union { unsigned u; float f; } v; v.u = ((unsigned)x) << 16; return v.f;
}

static __device__ __forceinline__ void gld_lds16(const void* g, void* l){
  __builtin_amdgcn_global_load_lds((const __attribute__((address_space(1))) unsigned int*)g,
                                   (__attribute__((address_space(3))) unsigned int*)l, 16, 0, 0);
}

// ---------------- fp32 -> bf16 conversion of q,k,v ----------------
__global__ void convx(const float* __restrict__ q, const float* __restrict__ k, const float* __restrict__ v,
                      u16* __restrict__ qb, u16* __restrict__ kb, u16* __restrict__ vb){
  const float* s = blockIdx.z==0 ? q : (blockIdx.z==1 ? k : v);
  u16* d = blockIdx.z==0 ? qb : (blockIdx.z==1 ? kb : vb);
  int i = (blockIdx.x*256 + threadIdx.x)*4;
  float4 f = *(const float4*)(s + i);
  ushort4 o; o.x=f2bf(f.x); o.y=f2bf(f.y); o.z=f2bf(f.z); o.w=f2bf(f.w);
  *(ushort4*)(d + i) = o;
}

// ------------- weight transpose + convert: Wt[n][k] = bf16(W[k][n]) -------------
__global__ void convw(const float* W0,const float* W1,const float* W2,const float* W3,const float* W4,
                      u16* T0,u16* T1,u16* T2,u16* T3,u16* T4){
  const float* W = blockIdx.z==0?W0:blockIdx.z==1?W1:blockIdx.z==2?W2:blockIdx.z==3?W3:W4;
  u16* T = blockIdx.z==0?T0:blockIdx.z==1?T1:blockIdx.z==2?T2:blockIdx.z==3?T3:T4;
  __shared__ u16 t[64][65];
  int k0 = blockIdx.x*64, n0 = blockIdx.y*64;
  for (int i=0;i<16;i++){
    int idx = i*256 + threadIdx.x;
    int r = idx >> 6, c = idx & 63;
    t[r][c] = f2bf(W[(size_t)(k0+r)*1024 + n0 + c]);
  }
  __syncthreads();
  for (int i=0;i<2;i++){
    int idx = i*256 + threadIdx.x;
    int nl = idx >> 3, kc = idx & 7;
    bf16x8 o;
    #pragma unroll
    for (int j=0;j<8;j++) o[j] = (short)t[kc*8+j][nl];
    *(bf16x8*)(T + (size_t)(n0+nl)*1024 + k0 + kc*8) = o;
  }
}

// ---------------- 128x128 bf16 MFMA GEMM, B pre-transposed (Bt[n][k]) ----------------
// MODE 0: bf16 row-major; 1: f32 row-major; 2: K attn layout (64-kv blocks);
// MODE 3: V attn layout (64-kv blocks); 4: bf16 row-major scaled by CL2 (Q)
template<int MODE>
static __device__ __forceinline__ void gemm_bt_dev(const u16* __restrict__ A, const u16* __restrict__ Bt,
                                                   const float* __restrict__ bias, void* __restrict__ Cout){
  __shared__ u16 As[128*32];
  __shared__ u16 Bs[128*32];
  const int tid = threadIdx.x, lane = tid & 63, w = tid >> 6;
  const int wm = w >> 1, wn = w & 1, quad = lane >> 4, lr = lane & 15;
  const int m0 = blockIdx.y * 128, n0 = blockIdx.x * 128;
  f32x4 acc[4][4] = {};
  const u16* Ab = A + (size_t)m0*1024;
  const u16* Bb = Bt + (size_t)n0*1024;
  const int srow = w*16 + (lane>>2);
  const int sg   = (lane & 3);
  for (int k0 = 0; k0 < 1024; k0 += 32){
    #pragma unroll
    for (int r = 0; r < 2; ++r){
      int row = r*64 + srow;
      int g = sg ^ ((row>>1)&3);
      gld_lds16(Ab + (size_t)row*1024 + k0 + g*8, As + (r*64 + w*16)*32);
      gld_lds16(Bb + (size_t)row*1024 + k0 + g*8, Bs + (r*64 + w*16)*32);
    }
    __syncthreads();
    bf16x8 af[4], bfr[4];
    #pragma unroll
    for (int i=0;i<4;i++){
      int rowa = wm*64 + i*16 + lr;
      af[i] = *(const bf16x8*)(As + rowa*32 + ((quad ^ ((rowa>>1)&3))*8));
      int rowb = wn*64 + i*16 + lr;
      bfr[i] = *(const bf16x8*)(Bs + rowb*32 + ((quad ^ ((rowb>>1)&3))*8));
    }
    #pragma unroll
    for (int mi=0;mi<4;mi++)
      #pragma unroll
      for (int ni=0;ni<4;ni++)
        acc[mi][ni] = __builtin_amdgcn_mfma_f32_16x16x32_bf16(af[mi], bfr[ni], acc[mi][ni], 0, 0, 0);
    __syncthreads();
  }
  #pragma unroll
  for (int mi=0;mi<4;mi++){
    int row = m0 + wm*64 + mi*16 + quad*4;
    #pragma unroll
    for (int ni=0;ni<4;ni++){
      int col = n0 + wn*64 + ni*16 + lr;
      float bb = bias[col];
      #pragma unroll
      for (int rg=0; rg<4; rg++){
        float vv = acc[mi][ni][rg] + bb;
        int r = row + rg;
        if (MODE == 0){
          ((u16*)Cout)[(size_t)r*1024 + col] = f2bf(vv);
        } else if (MODE == 4){
          ((u16*)Cout)[(size_t)r*1024 + col] = f2bf(vv * CL2);
        } else if (MODE == 1){
          ((float*)Cout)[(size_t)r*1024 + col] = vv;
        } else if (MODE == 2){
          // K: [bh][kb=32][hg=8][kvl=64][hl=8]
          int b2 = r >> 11, s = r & 2047, kb2 = s >> 6, kvl = s & 63;
          int hh = col >> 6, hg = (col & 63) >> 3, hl = col & 7;
          ((u16*)Cout)[((size_t)(b2*16+hh)*32 + kb2)*4096 + hg*512 + kvl*8 + hl] = f2bf(vv);
        } else {
          // V: [bh][kb=32][sg=16][dd=64][sl=4]
          int b2 = r >> 11, s = r & 2047, kb2 = s >> 6, kvl = s & 63;
          int sgv = kvl >> 2, sl = kvl & 3;
          int hh = col >> 6, dd = col & 63;
          ((u16*)Cout)[((size_t)(b2*16+hh)*32 + kb2)*4096 + sgv*256 + dd*4 + sl] = f2bf(vv);
        }
      }
    }
  }
}

__global__ void qkv_gemm(const u16* qb,const u16* kb,const u16* vb,
                         const u16* Wqt,const u16* Wkt,const u16* Wvt,
                         const float* bq,const float* bk,const float* bv,
                         u16* Qb,u16* Kr,u16* Vr){
  if (blockIdx.z == 0)      gemm_bt_dev<4>(qb, Wqt, bq, Qb);   // Q pre-scaled by CL2
  else if (blockIdx.z == 1) gemm_bt_dev<2>(kb, Wkt, bk, Kr);
  else                      gemm_bt_dev<3>(vb, Wvt, bv, Vr);
}

__global__ void out_gemm(const u16* Mg, const u16* Wct, const u16* Wot,
                         const float* bc, const float* bo, float* out){
  const u16* B = blockIdx.z==0? Wct : Wot;
  const float* bias = blockIdx.z==0? bc : bo;
  float* C = out + (blockIdx.z==0? 0 : 4194304);   // (c, h) concatenated
  gemm_bt_dev<1>(Mg, B, bias, C);
}

// ---------------- flash attention, transposed-score, no-max softmax, kv-split ----------------
// grid (16 qt, 32 bh, 2 split) = 1024 blocks -> 4 blocks/CU = 16 waves/CU (4/SIMD).
// block = 256 threads (4 waves); each wave owns 32 q (two 16-q B-frags).
// KV-block 64, LDS 32 KB double-buffered. Buffers are 8 KB each -> TWO gld_lds16
// chunks per thread per buffer (R5 bug: one chunk staged only half; stale LDS = NaN).
__global__ __launch_bounds__(256,4) void attn(const u16* __restrict__ Qb, const u16* __restrict__ Kr,
                                              const u16* __restrict__ Vr,
                                              u16* __restrict__ O0, u16* __restrict__ O1,
                                              float* __restrict__ l0, float* __restrict__ l1){
  __shared__ u16 Ks[2][4096];
  __shared__ u16 Vs[2][4096];
  const int qt = blockIdx.x, bh = blockIdx.y, sp = blockIdx.z;
  const int b = bh >> 4, h = bh & 15;
  const int tid = threadIdx.x, lane = tid & 63, w = tid >> 6;
  const int quad = lane >> 4, lr = lane & 15;
  const int q0 = qt*128 + w*32;

  bf16x8 aq[2][2];   // [q-subtile][ks]; Q pre-scaled by CL2
  #pragma unroll
  for (int t=0;t<2;t++)
    #pragma unroll
    for (int ks=0;ks<2;ks++)
      aq[t][ks] = *(const bf16x8*)(Qb + (size_t)(b*2048 + q0 + t*16 + lr)*1024 + h*64 + ks*32 + quad*8);

  f32x4 acco[2][4] = {};
  f32x4 accl[2] = {};
  const bf16x4 ones = {(short)0x3F80,(short)0x3F80,(short)0x3F80,(short)0x3F80};

  const u16* Krb = Kr + (size_t)bh*131072 + (size_t)sp*65536;  // 16 kv-64 blocks * 4096
  const u16* Vrb = Vr + (size_t)bh*131072 + (size_t)sp*65536;

  // prefetch kv-block 0: 2 chunks x 4 KB per 8 KB buffer
  #pragma unroll
  for (int j=0;j<2;j++){
    gld_lds16(Krb + j*2048 + tid*8, &Ks[0][j*2048 + w*512]);
    gld_lds16(Vrb + j*2048 + tid*8, &Vs[0][j*2048 + w*512]);
  }

  for (int kb = 0; kb < 16; kb++){
    __syncthreads();
    const int cur = kb & 1;
    if (kb < 15){
      const u16* kg = Krb + (size_t)(kb+1)*4096;
      const u16* vg = Vrb + (size_t)(kb+1)*4096;
      #pragma unroll
      for (int j=0;j<2;j++){
        gld_lds16(kg + j*2048 + tid*8, &Ks[cur^1][j*2048 + w*512]);
        gld_lds16(vg + j*2048 + tid*8, &Vs[cur^1][j*2048 + w*512]);
      }
    }
    const u16* Ksc = Ks[cur];
    const u16* Vsc = Vs[cur];

    // ---- per-mt: S^T (16 kv x 32 q) then immediately exp+pack (short dep chains) ----
    bf16x4 pf[2][4];
    #pragma unroll
    for (int mt=0;mt<4;mt++){
      bf16x8 kf0 = *(const bf16x8*)(Ksc + quad*512     + (mt*16+lr)*8);
      bf16x8 kf1 = *(const bf16x8*)(Ksc + (4+quad)*512 + (mt*16+lr)*8);
      f32x4 a0 = {}, a1 = {};
      a0 = __builtin_amdgcn_mfma_f32_16x16x32_bf16(kf0, aq[0][0], a0, 0,0,0);
      a1 = __builtin_amdgcn_mfma_f32_16x16x32_bf16(kf0, aq[1][0], a1, 0,0,0);
      a0 = __builtin_amdgcn_mfma_f32_16x16x32_bf16(kf1, aq[0][1], a0, 0,0,0);
      a1 = __builtin_amdgcn_mfma_f32_16x16x32_bf16(kf1, aq[1][1], a1, 0,0,0);
      #pragma unroll
      for (int t=0;t<2;t++){
        const f32x4& a = t ? a1 : a0;
        float p0 = __builtin_amdgcn_exp2f(a[0]);
        float p1 = __builtin_amdgcn_exp2f(a[1]);
        float p2 = __builtin_amdgcn_exp2f(a[2]);
        float p3 = __builtin_amdgcn_exp2f(a[3]);
        unsigned u0 = __float_as_uint(p0) + 0x8000u;
        unsigned u1 = __float_as_uint(p1) + 0x8000u;
        unsigned u2 = __float_as_uint(p2) + 0x8000u;
        unsigned u3 = __float_as_uint(p3) + 0x8000u;
        union { int2 i2; bf16x4 v; } pk;
        pk.i2.x = (int)__builtin_amdgcn_perm(u1, u0, 0x07060302u);
        pk.i2.y = (int)__builtin_amdgcn_perm(u3, u2, 0x07060302u);
        pf[t][mt] = pk.v;
      }
    }

    // ---- l via MFMA: accl += ones^T * P^T ----
    #pragma unroll
    for (int mt=0;mt<4;mt++){
      accl[0] = __builtin_amdgcn_mfma_f32_16x16x16bf16_1k(ones, pf[0][mt], accl[0], 0,0,0);
      accl[1] = __builtin_amdgcn_mfma_f32_16x16x16bf16_1k(ones, pf[1][mt], accl[1], 0,0,0);
    }

    // ---- O^T += V^T * P^T (each vf feeds both q-subtiles) ----
    #pragma unroll
    for (int dt=0;dt<4;dt++){
      #pragma unroll
      for (int mt=0;mt<4;mt++){
        bf16x4 vf = *(const bf16x4*)(Vsc + (mt*4+quad)*256 + (dt*16+lr)*4);
        acco[0][dt] = __builtin_amdgcn_mfma_f32_16x16x16bf16_1k(vf, pf[0][mt], acco[0][dt], 0,0,0);
        acco[1][dt] = __builtin_amdgcn_mfma_f32_16x16x16bf16_1k(vf, pf[1][mt], acco[1][dt], 0,0,0);
      }
    }
  }

  // ---- epilogue: write unnormalized partial O (bf16) + partial l (f32) ----
  u16* Op = sp ? O1 : O0;
  float* lp = sp ? l1 : l0;
  #pragma unroll
  for (int t=0;t<2;t++){
    u16* dst = Op + (size_t)(b*2048 + q0 + t*16 + lr)*1024 + h*64;
    #pragma unroll
    for (int dt=0;dt<4;dt++){
      bf16x4 o;
      #pragma unroll
      for (int rg=0;rg<4;rg++) o[rg] = (short)f2bf(acco[t][dt][rg]);
      *(bf16x4*)(dst + dt*16 + quad*4) = o;
    }
    if (quad == 0) lp[(size_t)bh*2048 + q0 + t*16 + lr] = accl[t][0];
  }
}

// ---------------- combine: Mg = (O0+O1)/(l0+l1) ----------------
__global__ void combine(const u16* __restrict__ O0, const u16* __restrict__ O1,
                        const float* __restrict__ l0, const float* __restrict__ l1,
                        u16* __restrict__ Mg){
  int i = (blockIdx.x*256 + threadIdx.x)*8;
  int row = i >> 10, col = i & 1023;
  int b = row >> 11, q = row & 2047, h = col >> 6;
  size_t li = (size_t)(b*16+h)*2048 + q;
  float inv = 1.f / (l0[li] + l1[li]);
  bf16x8 a = *(const bf16x8*)(O0 + i);
  bf16x8 c = *(const bf16x8*)(O1 + i);
  bf16x8 o;
  #pragma unroll
  for (int j=0;j<8;j++)
    o[j] = (short)f2bf((bf2f((u16)a[j]) + bf2f((u16)c[j])) * inv);
  *(bf16x8*)(Mg + i) = o;
}

extern "C" void kernel_launch(void* const* d_in, const int* in_sizes, int n_in,
                              void* d_out, int out_size, void* d_ws, size_t ws_size,
                              hipStream_t stream){
  const float* q  = (const float*)d_in[0];
  const float* k  = (const float*)d_in[1];
  const float* v  = (const float*)d_in[2];
  const float* Wq = (const float*)d_in[3];
  const float* bq = (const float*)d_in[4];
  const float* Wk = (const float*)d_in[5];
  const float* bk = (const float*)d_in[6];
  const float* Wv = (const float*)d_in[7];
  const float* bv = (const float*)d_in[8];
  const float* Wo = (const float*)d_in[9];
  const float* bo = (const float*)d_in[10];
  const float* Wc = (const float*)d_in[11];
  const float* bc = (const float*)d_in[12];
  char* ws = (char*)d_ws;
  u16* qb  = (u16*)(ws + (size_t)0*MB);    // dead after qkv_gemm -> reused by O0
  u16* kb  = (u16*)(ws + (size_t)8*MB);    // dead after qkv_gemm -> reused by O1
  u16* vb  = (u16*)(ws + (size_t)16*MB);   // dead after qkv_gemm -> reused by l0/l1
  u16* Wqt = (u16*)(ws + (size_t)24*MB);
  u16* Wkt = (u16*)(ws + (size_t)26*MB);
  u16* Wvt = (u16*)(ws + (size_t)28*MB);
  u16* Wot = (u16*)(ws + (size_t)30*MB);
  u16* Wct = (u16*)(ws + (size_t)32*MB);
  u16* Qb  = (u16*)(ws + (size_t)34*MB);
  u16* Kr  = (u16*)(ws + (size_t)42*MB);
  u16* Vr  = (u16*)(ws + (size_t)50*MB);
  u16* Mg  = (u16*)(ws + (size_t)58*MB);
  u16* O0  = (u16*)(ws + (size_t)0*MB);
  u16* O1  = (u16*)(ws + (size_t)8*MB);
  float* l0 = (float*)(ws + (size_t)16*MB);
  float* l1 = (float*)(ws + (size_t)17*MB);

  dim3 blk(256,1,1);
  hipLaunchKernelGGL(convx,    dim3(4096,1,3), blk, 0, stream, q,k,v, qb,kb,vb);
  hipLaunchKernelGGL(convw,    dim3(16,16,5),  blk, 0, stream, Wq,Wk,Wv,Wo,Wc, Wqt,Wkt,Wvt,Wot,Wct);
  hipLaunchKernelGGL(qkv_gemm, dim3(8,32,3),   blk, 0, stream, qb,kb,vb, Wqt,Wkt,Wvt, bq,bk,bv, Qb,Kr,Vr);
  hipLaunchKernelGGL(attn,     dim3(16,32,2),  blk, 0, stream, Qb, Kr, Vr, O0, O1, l0, l1);
  hipLaunchKernelGGL(combine,  dim3(2048,1,1), blk, 0, stream, O0, O1, l0, l1, Mg);
  hipLaunchKernelGGL(out_gemm, dim3(8,32,2),   blk, 0, stream, Mg, Wct, Wot, bc, bo, (float*)d_out);
}